// Round 2
// baseline (375.107 us; speedup 1.0000x reference)
//
#include <hip/hip_runtime.h>
#include <hip/hip_bf16.h>

#define BS   2
#define SEQ  2048
#define DIM  1024
#define HD   32
#define G    8
#define HPG  4
#define KVD  256
#define NTOT (DIM + 2*KVD)   // 1536 output cols of the fused QKV GEMM

typedef __attribute__((ext_vector_type(8))) _Float16 f16x8;
typedef __attribute__((ext_vector_type(4))) float f32x4;

__device__ __forceinline__ unsigned short f2h(float f) {
    _Float16 h = (_Float16)f;   // v_cvt_f16_f32, RTE
    return __builtin_bit_cast(unsigned short, h);
}

// ---------------- fp32 -> fp16 convert (vectorized, grid-stride) ----------------
__global__ __launch_bounds__(256) void cvt_kernel(const float* __restrict__ in,
                                                  unsigned short* __restrict__ out, int n) {
    int nv = n >> 2;
    for (int i = blockIdx.x * blockDim.x + threadIdx.x; i < nv; i += gridDim.x * blockDim.x) {
        float4 v = reinterpret_cast<const float4*>(in)[i];
        ushort4 o;
        o.x = f2h(v.x); o.y = f2h(v.y); o.z = f2h(v.z); o.w = f2h(v.w);
        reinterpret_cast<ushort4*>(out)[i] = o;
    }
}

// ---------------- fused QKV projection GEMM ----------------
// Y[m][n] = sum_k X[m][k] * W[n][k],  M=4096, N=1536, K=1024
// block = 4 waves, tile 64x64; wave w owns rows m0+w*16, 4 n-frags of 16.
// Epilogue routes cols: [0,1024)->qb, [1024,1280)->kb, [1280,1536)->vtb (transposed).
__global__ __launch_bounds__(256) void qkv_gemm(const unsigned short* __restrict__ xb,
                                                const unsigned short* __restrict__ wb,
                                                unsigned short* __restrict__ qb,
                                                unsigned short* __restrict__ kb,
                                                unsigned short* __restrict__ vtb) {
    int lane = threadIdx.x & 63;
    int w    = threadIdx.x >> 6;
    int m0   = blockIdx.y * 64 + w * 16;
    int n0   = blockIdx.x * 64;
    int lr = lane & 15, lq = lane >> 4;

    f32x4 acc[4] = {};
    const unsigned short* xrow = xb + (m0 + lr) * DIM + lq * 8;
    for (int ks = 0; ks < DIM; ks += 32) {
        f16x8 a = *reinterpret_cast<const f16x8*>(xrow + ks);
        #pragma unroll
        for (int nf = 0; nf < 4; nf++) {
            const unsigned short* wrow = wb + (n0 + nf * 16 + lr) * DIM + ks + lq * 8;
            f16x8 bfr = *reinterpret_cast<const f16x8*>(wrow);
            acc[nf] = __builtin_amdgcn_mfma_f32_16x16x32_f16(a, bfr, acc[nf], 0, 0, 0);
        }
    }
    #pragma unroll
    for (int nf = 0; nf < 4; nf++) {
        int col = n0 + nf * 16 + lr;
        #pragma unroll
        for (int r = 0; r < 4; r++) {
            int row = m0 + lq * 4 + r;
            unsigned short v = f2h(acc[nf][r]);
            if (col < DIM) {
                qb[row * DIM + col] = v;
            } else if (col < DIM + KVD) {
                kb[row * KVD + (col - DIM)] = v;
            } else {
                int b = row >> 11, s = row & 2047;
                vtb[(b * KVD + (col - DIM - KVD)) * SEQ + s] = v;
            }
        }
    }
}

// ---------------- flash-style GQA attention ----------------
// block = one (b, g, 64-row q-tile); 4 waves = the 4 heads of the group.
// Per wave: 4 row-frags (16 rows) x full 32-dim head. KVBLK = 32.
__global__ __launch_bounds__(256) void gqa_attn(const unsigned short* __restrict__ qb,
                                                const unsigned short* __restrict__ kb,
                                                const unsigned short* __restrict__ vtb,
                                                float* __restrict__ out) {
    __shared__ unsigned short p_lds[4][64][32];
    int lane = threadIdx.x & 63;
    int w    = threadIdx.x >> 6;
    int bi   = blockIdx.x;
    int qt = bi & 31;
    int g  = (bi >> 5) & 7;
    int b  = bi >> 8;
    int q0 = qt * 64;
    int lr = lane & 15, lq = lane >> 4;

    // Q fragments (A-operand: row = lane&15, k = (lane>>4)*8+j)
    f16x8 qf[4];
    #pragma unroll
    for (int t = 0; t < 4; t++) {
        int row = q0 + t * 16 + lr;
        qf[t] = *reinterpret_cast<const f16x8*>(
            qb + (b * SEQ + row) * DIM + (g * HPG + w) * HD + lq * 8);
    }

    f32x4 O[4][2] = {};
    float m[4][4], l[4][4];
    #pragma unroll
    for (int t = 0; t < 4; t++)
        #pragma unroll
        for (int r = 0; r < 4; r++) { m[t][r] = -1e30f; l[t][r] = 0.f; }

    const unsigned short* kbase = kb + b * SEQ * KVD + g * HD;
    const unsigned short* vbase = vtb + (b * KVD + g * HD) * SEQ;

    for (int kt = 0; kt < SEQ; kt += 32) {
        // K fragments (B-operand: col = key = lane&15 (+16), k = d = (lane>>4)*8+j)
        f16x8 kf0 = *reinterpret_cast<const f16x8*>(kbase + (kt + lr) * KVD + lq * 8);
        f16x8 kf1 = *reinterpret_cast<const f16x8*>(kbase + (kt + 16 + lr) * KVD + lq * 8);

        #pragma unroll
        for (int t = 0; t < 4; t++) {
            f32x4 z = {};
            f32x4 s0 = __builtin_amdgcn_mfma_f32_16x16x32_f16(qf[t], kf0, z, 0, 0, 0);
            f32x4 s1 = __builtin_amdgcn_mfma_f32_16x16x32_f16(qf[t], kf1, z, 0, 0, 0);
            #pragma unroll
            for (int r = 0; r < 4; r++) {
                // C-layout: this lane's reg r is row lq*4+r, col lr (keys kt+lr, kt+16+lr)
                float tm = fmaxf(s0[r], s1[r]);
                #pragma unroll
                for (int off = 1; off < 16; off <<= 1) tm = fmaxf(tm, __shfl_xor(tm, off, 64));
                float mn = fmaxf(m[t][r], tm);
                float sc = __expf(m[t][r] - mn);
                m[t][r] = mn;
                float p0 = __expf(s0[r] - mn);
                float p1 = __expf(s1[r] - mn);
                float rs = p0 + p1;
                #pragma unroll
                for (int off = 1; off < 16; off <<= 1) rs += __shfl_xor(rs, off, 64);
                l[t][r] = l[t][r] * sc + rs;
                O[t][0][r] *= sc;
                O[t][1][r] *= sc;
                int row = lq * 4 + r;
                p_lds[w][t * 16 + row][lr]      = f2h(p0);
                p_lds[w][t * 16 + row][lr + 16] = f2h(p1);
            }
        }
        asm volatile("s_waitcnt lgkmcnt(0)" ::: "memory");
        __builtin_amdgcn_sched_barrier(0);

        // V^T fragments (B-operand: col = d = lane&15 (+16), k = key = (lane>>4)*8+j)
        f16x8 vf0 = *reinterpret_cast<const f16x8*>(vbase + lr * SEQ + kt + lq * 8);
        f16x8 vf1 = *reinterpret_cast<const f16x8*>(vbase + (16 + lr) * SEQ + kt + lq * 8);

        #pragma unroll
        for (int t = 0; t < 4; t++) {
            f16x8 pa = *reinterpret_cast<const f16x8*>(&p_lds[w][t * 16 + lr][lq * 8]);
            O[t][0] = __builtin_amdgcn_mfma_f32_16x16x32_f16(pa, vf0, O[t][0], 0, 0, 0);
            O[t][1] = __builtin_amdgcn_mfma_f32_16x16x32_f16(pa, vf1, O[t][1], 0, 0, 0);
        }
    }

    // epilogue: out[b, row, (g*4+w)*32 + d] = O / l
    float* obase = out + (size_t)(b * SEQ) * DIM + (g * HPG + w) * HD;
    #pragma unroll
    for (int t = 0; t < 4; t++) {
        #pragma unroll
        for (int r = 0; r < 4; r++) {
            int row = q0 + t * 16 + lq * 4 + r;
            float inv = 1.0f / l[t][r];
            obase[(size_t)row * DIM + lr]      = O[t][0][r] * inv;
            obase[(size_t)row * DIM + 16 + lr] = O[t][1][r] * inv;
        }
    }
}

extern "C" void kernel_launch(void* const* d_in, const int* in_sizes, int n_in,
                              void* d_out, int out_size, void* d_ws, size_t ws_size,
                              hipStream_t stream) {
    const float* x  = (const float*)d_in[0];
    const float* wq = (const float*)d_in[1];
    const float* wk = (const float*)d_in[2];
    const float* wv = (const float*)d_in[3];
    float* out = (float*)d_out;

    unsigned short* ws  = (unsigned short*)d_ws;
    unsigned short* xb  = ws;                                  // 4096*1024
    unsigned short* wb  = xb + (size_t)BS * SEQ * DIM;         // 1536*1024
    unsigned short* qb  = wb + (size_t)NTOT * DIM;             // 4096*1024
    unsigned short* kb  = qb + (size_t)BS * SEQ * DIM;         // 4096*256
    unsigned short* vtb = kb + (size_t)BS * SEQ * KVD;         // 4096*256 (transposed)

    cvt_kernel<<<1024, 256, 0, stream>>>(x, xb, BS * SEQ * DIM);
    cvt_kernel<<<256,  256, 0, stream>>>(wq, wb, DIM * DIM);
    cvt_kernel<<<64,   256, 0, stream>>>(wk, wb + (size_t)DIM * DIM, KVD * DIM);
    cvt_kernel<<<64,   256, 0, stream>>>(wv, wb + (size_t)DIM * DIM + (size_t)KVD * DIM, KVD * DIM);

    qkv_gemm<<<dim3(NTOT / 64, BS * SEQ / 64), 256, 0, stream>>>(xb, wb, qb, kb, vtb);
    gqa_attn<<<BS * G * (SEQ / 64), 256, 0, stream>>>(qb, kb, vtb, out);
}